// Round 1
// baseline (176.738 us; speedup 1.0000x reference)
//
#include <hip/hip_runtime.h>
#include <math.h>

// Problem constants
#define NSAMP 32768   // 2^15 = 8^5
#define NDEL  512
#define NFR   16
#define BATCH 8

__device__ __forceinline__ float2 cmul(float2 a, float2 b) {
    return make_float2(a.x*b.x - a.y*b.y, a.x*b.y + a.y*b.x);
}
__device__ __forceinline__ float2 cadd(float2 a, float2 b){ return make_float2(a.x+b.x, a.y+b.y); }
__device__ __forceinline__ float2 csub(float2 a, float2 b){ return make_float2(a.x-b.x, a.y-b.y); }
// multiply by sign*i : fwd(sign=-1) -> -i*z = (y,-x) ; inv(+1) -> +i*z = (-y,x)
__device__ __forceinline__ float2 crot(float2 z, float sign){ return make_float2(-sign*z.y, sign*z.x); }

// ---------------------------------------------------------------------------
// softmax over the 512 delays for each (batch, frame), with the per-batch
// damping constant folded in (powers = linspace(1,1,16) == ones in the ref).
// W layout: [b][f][i] contiguous in i.
__global__ void softmax_damp_kernel(const float* __restrict__ dsel,
                                    const float* __restrict__ damping,
                                    float* __restrict__ W) {
    int bf = blockIdx.x;          // [0, 8*16)
    int b = bf >> 4, f = bf & 15;
    int i = threadIdx.x;          // [0, 512)
    __shared__ float red[NDEL];
    float v = dsel[(b*NDEL + i)*NFR + f];
    red[i] = v;
    __syncthreads();
    for (int off = 256; off > 0; off >>= 1) {
        if (i < off) red[i] = fmaxf(red[i], red[i+off]);
        __syncthreads();
    }
    float M = red[0];
    __syncthreads();
    float e = expf(v - M);
    red[i] = e;
    __syncthreads();
    for (int off = 256; off > 0; off >>= 1) {
        if (i < off) red[i] += red[i+off];
        __syncthreads();
    }
    float S = red[0];
    float damp = 1.0f/(1.0f + expf(-damping[b])) * 0.9999f;
    W[(b*NFR + f)*NDEL + i] = e / S * damp;
}

// ---------------------------------------------------------------------------
// Build packed complex signal z = d + i*imp per batch.
// d[b,n] = sum over divisors t<=512 of n of W[b, n>>11, t-1]   (delays[i,::i+1]=1)
// imp[b,n] = linear-interp(impulse[b]^2, 128->32768)[n] * noise[b,n]
__global__ void build_kernel(const float* __restrict__ impulse,
                             const float* __restrict__ damping,
                             const float* __restrict__ noise,
                             const float* __restrict__ W,
                             float2* __restrict__ A) {
    int gid = blockIdx.x * 256 + threadIdx.x;   // [0, 8*32768)
    int b = gid >> 15;
    int n = gid & (NSAMP - 1);
    int f = n >> 11;                            // nearest upsample 16 -> 32768
    __shared__ float Wrow[NDEL];                // b,f uniform per 256-block
    const float* Wp = W + (b*NFR + f)*NDEL;
    for (int t = threadIdx.x; t < NDEL; t += 256) Wrow[t] = Wp[t];
    __syncthreads();

    float dval;
    if (n == 0) {
        // every delay divides 0; softmax sums to 1 -> d = damp
        dval = 1.0f/(1.0f + expf(-damping[b])) * 0.9999f;
    } else {
        dval = 0.0f;
        unsigned un = (unsigned)n;
        for (unsigned t = 1; t*t <= un; ++t) {     // t <= 181 <= 512 always
            if (un % t == 0u) {
                dval += Wrow[t-1];
                unsigned u = un / t;
                if (u != t && u <= NDEL) dval += Wrow[u-1];
            }
        }
    }

    // impulse^2 linear interp (align_corners=False), scale = 128/32768 = 1/256
    float pos = (n + 0.5f) * (1.0f/256.0f) - 0.5f;
    pos = fminf(fmaxf(pos, 0.0f), 127.0f);
    int i0 = (int)pos;
    float w = pos - (float)i0;
    int i1 = (i0 + 1 > 127) ? 127 : i0 + 1;
    float x0 = impulse[b*128 + i0]; x0 *= x0;
    float x1 = impulse[b*128 + i1]; x1 *= x1;
    float iv = (x0*(1.0f - w) + x1*w) * noise[gid];

    A[gid] = make_float2(dval, iv);
}

// ---------------------------------------------------------------------------
// Radix-8 Stockham stage. N = 32768 = 8^5, 5 stages: lNs = 0,3,6,9,12.
// sign = -1 forward, +1 inverse (unnormalized). 8 signals, grid = 8*4096 thr.
// If out_real != nullptr (last inverse stage), store only Re -> d_out.
__global__ void fft_stage(const float2* __restrict__ src,
                          float2* __restrict__ dst,
                          float* __restrict__ out_real,
                          int lNs, float sign) {
    const float S2 = 0.70710678118654752f;
    int gid = blockIdx.x * 256 + threadIdx.x;
    int j = gid & 4095;           // N/8 = 4096
    int s = gid >> 12;            // signal
    const float2* sp = src + s * NSAMP;
    float2 v[8];
#pragma unroll
    for (int q = 0; q < 8; ++q) v[q] = sp[j + (q << 12)];

    int Nsub = 1 << lNs;
    int jm = j & (Nsub - 1);
    if (lNs > 0) {
        float a = sign * 6.283185307179586f * (float)jm / (float)(Nsub << 3);
        float sa, ca;
        __sincosf(a, &sa, &ca);
        float2 w1 = make_float2(ca, sa);
        float2 wq = w1;
#pragma unroll
        for (int q = 1; q < 8; ++q) { v[q] = cmul(v[q], wq); wq = cmul(wq, w1); }
    }

    // DFT-8: evens (v0,v2,v4,v6), odds (v1,v3,v5,v7), two FFT4 + combine
    float2 t0 = cadd(v[0], v[4]), t1 = csub(v[0], v[4]);
    float2 t2 = cadd(v[2], v[6]), t3 = crot(csub(v[2], v[6]), sign);
    float2 E0 = cadd(t0, t2), E1 = cadd(t1, t3), E2 = csub(t0, t2), E3 = csub(t1, t3);
    float2 u0 = cadd(v[1], v[5]), u1 = csub(v[1], v[5]);
    float2 u2 = cadd(v[3], v[7]), u3 = crot(csub(v[3], v[7]), sign);
    float2 O0 = cadd(u0, u2), O1 = cadd(u1, u3), O2 = csub(u0, u2), O3 = csub(u1, u3);
    float2 c1 = make_float2( S2, sign*S2);
    float2 c3 = make_float2(-S2, sign*S2);
    float2 w1o = cmul(c1, O1);
    float2 w2o = crot(O2, sign);
    float2 w3o = cmul(c3, O3);
    float2 X[8];
    X[0] = cadd(E0, O0);  X[4] = csub(E0, O0);
    X[1] = cadd(E1, w1o); X[5] = csub(E1, w1o);
    X[2] = cadd(E2, w2o); X[6] = csub(E2, w2o);
    X[3] = cadd(E3, w3o); X[7] = csub(E3, w3o);

    int idxD = ((j >> lNs) << (lNs + 3)) + jm;
    if (out_real) {
        float* op = out_real + s * NSAMP + idxD;
#pragma unroll
        for (int r = 0; r < 8; ++r) op[r << lNs] = X[r].x;
    } else {
        float2* dp = dst + s * NSAMP + idxD;
#pragma unroll
        for (int r = 0; r < 8; ++r) dp[r << lNs] = X[r];
    }
}

// ---------------------------------------------------------------------------
// Unpack Z = DFT(d + i*imp) into D, I via Hermitian split; multiply with the
// filter envelope (sigmoid->linear interp 16 -> 16384, bin 16384 padded 0,
// mirrored for k > N/2) and the combined ortho scale N^{-3/2}. Writes full
// Hermitian spectrum -> inverse FFT input.
__global__ void pointwise_kernel(const float2* __restrict__ Z,
                                 const float* __restrict__ filt,
                                 float2* __restrict__ A) {
    int gid = blockIdx.x * 256 + threadIdx.x; // [0, 8*32768)
    int b = gid >> 15;                        // uniform per block
    int k = gid & (NSAMP - 1);
    __shared__ float fs[NFR];
    if (threadIdx.x < NFR)
        fs[threadIdx.x] = 1.0f/(1.0f + expf(-filt[b*NFR + threadIdx.x]));
    __syncthreads();

    const float2* Zp = Z + b * NSAMP;
    float2 Zk = Zp[k];
    float2 Zr = Zp[(NSAMP - k) & (NSAMP - 1)];
    float2 Zrc = make_float2(Zr.x, -Zr.y);              // conj(Z[N-k])
    float2 D = make_float2(0.5f*(Zk.x + Zrc.x), 0.5f*(Zk.y + Zrc.y));
    float2 df = make_float2(Zk.x - Zrc.x, Zk.y - Zrc.y);
    float2 I = make_float2(0.5f*df.y, -0.5f*df.x);      // -i/2 * (Zk - conj(Zr))

    int jj = (k <= NSAMP - k) ? k : NSAMP - k;          // rfft bin index
    float fv = 0.0f;
    if (jj < NSAMP/2) {   // jj == 16384 is the zero-padded bin
        float pos = (jj + 0.5f) * (1.0f/1024.0f) - 0.5f; // scale = 16/16384
        pos = fminf(fmaxf(pos, 0.0f), 15.0f);
        int i0 = (int)pos;
        float w = pos - (float)i0;
        int i1 = (i0 + 1 > 15) ? 15 : i0 + 1;
        fv = fs[i0]*(1.0f - w) + fs[i1]*w;
    }
    const float SCALE = 1.0f / (32768.0f * 181.01933598375618f); // N^{-3/2}
    float2 spec = cmul(D, I);
    float g = fv * SCALE;
    A[gid] = make_float2(spec.x * g, spec.y * g);
}

// ---------------------------------------------------------------------------
extern "C" void kernel_launch(void* const* d_in, const int* in_sizes, int n_in,
                              void* d_out, int out_size, void* d_ws, size_t ws_size,
                              hipStream_t stream) {
    const float* impulse = (const float*)d_in[0];   // [8,128]
    const float* dsel    = (const float*)d_in[1];   // [8,512,16]
    const float* damping = (const float*)d_in[2];   // [8,1]
    const float* filt    = (const float*)d_in[3];   // [8,16]
    const float* noise   = (const float*)d_in[4];   // [8,1,32768]
    // d_in[5] (delays, 64 MB) is pure structure: delays[i,n] = ((i+1) | n) — unused.
    float* out = (float*)d_out;                     // [8,32768]

    float2* A = (float2*)d_ws;                      // 8*32768 complex = 2 MB
    float2* B = A + BATCH * NSAMP;                  // 2 MB
    float*  W = (float*)(B + BATCH * NSAMP);        // 8*16*512 floats = 256 KB

    softmax_damp_kernel<<<dim3(BATCH*NFR), dim3(NDEL), 0, stream>>>(dsel, damping, W);
    build_kernel<<<dim3(BATCH*NSAMP/256), dim3(256), 0, stream>>>(impulse, damping, noise, W, A);

    // forward FFT (sign=-1) of 8 packed signals: A->B->A->B->A->B
    fft_stage<<<dim3(128), dim3(256), 0, stream>>>(A, B, nullptr,  0, -1.0f);
    fft_stage<<<dim3(128), dim3(256), 0, stream>>>(B, A, nullptr,  3, -1.0f);
    fft_stage<<<dim3(128), dim3(256), 0, stream>>>(A, B, nullptr,  6, -1.0f);
    fft_stage<<<dim3(128), dim3(256), 0, stream>>>(B, A, nullptr,  9, -1.0f);
    fft_stage<<<dim3(128), dim3(256), 0, stream>>>(A, B, nullptr, 12, -1.0f);

    pointwise_kernel<<<dim3(BATCH*NSAMP/256), dim3(256), 0, stream>>>(B, filt, A);

    // inverse FFT (sign=+1, unnormalized — scale folded into pointwise);
    // last stage writes Re() directly to d_out.
    fft_stage<<<dim3(128), dim3(256), 0, stream>>>(A, B, nullptr,  0, 1.0f);
    fft_stage<<<dim3(128), dim3(256), 0, stream>>>(B, A, nullptr,  3, 1.0f);
    fft_stage<<<dim3(128), dim3(256), 0, stream>>>(A, B, nullptr,  6, 1.0f);
    fft_stage<<<dim3(128), dim3(256), 0, stream>>>(B, A, nullptr,  9, 1.0f);
    fft_stage<<<dim3(128), dim3(256), 0, stream>>>(A, B, out,     12, 1.0f);
}

// Round 2
// 148.295 us; speedup vs baseline: 1.1918x; 1.1918x over previous
//
#include <hip/hip_runtime.h>
#include <math.h>

#define NSAMP 32768   // 2^15 = 512 * 64
#define NDEL  512
#define NFR   16
#define BATCH 8
#define TWO_PI 6.283185307179586f

__device__ __forceinline__ float2 cmul(float2 a, float2 b) {
    return make_float2(a.x*b.x - a.y*b.y, a.x*b.y + a.y*b.x);
}
__device__ __forceinline__ float2 cadd(float2 a, float2 b){ return make_float2(a.x+b.x, a.y+b.y); }
__device__ __forceinline__ float2 csub(float2 a, float2 b){ return make_float2(a.x-b.x, a.y-b.y); }
// multiply by sign*i : fwd(sign=-1) -> -i*z = (y,-x) ; inv(+1) -> +i*z = (-y,x)
__device__ __forceinline__ float2 crot(float2 z, float sign){ return make_float2(-sign*z.y, sign*z.x); }

// LDS index swizzle to break power-of-2 strides (i -> i + i/8)
__device__ __forceinline__ int phi(int i){ return i + (i >> 3); }

__device__ __forceinline__ void bfly8(const float2 v[8], float sign, float2 X[8]) {
    const float S2 = 0.70710678118654752f;
    float2 t0 = cadd(v[0], v[4]), t1 = csub(v[0], v[4]);
    float2 t2 = cadd(v[2], v[6]), t3 = crot(csub(v[2], v[6]), sign);
    float2 E0 = cadd(t0, t2), E1 = cadd(t1, t3), E2 = csub(t0, t2), E3 = csub(t1, t3);
    float2 u0 = cadd(v[1], v[5]), u1 = csub(v[1], v[5]);
    float2 u2 = cadd(v[3], v[7]), u3 = crot(csub(v[3], v[7]), sign);
    float2 O0 = cadd(u0, u2), O1 = cadd(u1, u3), O2 = csub(u0, u2), O3 = csub(u1, u3);
    float2 c1 = make_float2( S2, sign*S2);
    float2 c3 = make_float2(-S2, sign*S2);
    float2 w1o = cmul(c1, O1);
    float2 w2o = crot(O2, sign);
    float2 w3o = cmul(c3, O3);
    X[0]=cadd(E0,O0);  X[4]=csub(E0,O0);
    X[1]=cadd(E1,w1o); X[5]=csub(E1,w1o);
    X[2]=cadd(E2,w2o); X[6]=csub(E2,w2o);
    X[3]=cadd(E3,w3o); X[7]=csub(E3,w3o);
}

__device__ __forceinline__ void twiddle_q(float2 v[8], float ang1) {
    float sa, ca; __sincosf(ang1, &sa, &ca);
    float2 w1 = make_float2(ca, sa), wq = w1;
#pragma unroll
    for (int q = 1; q < 8; ++q) { v[q] = cmul(v[q], wq); wq = cmul(wq, w1); }
}

// ---------------------------------------------------------------------------
// Fused softmax + damping + divisor-sieve + impulse/noise build.
// One block per (b, f): 2048-sample window. d[n] = sum_{t | n, t<=512} W[t-1],
// built by sieving multiples of t into an LDS accumulator.
__global__ void build_kernel(const float* __restrict__ impulse,
                             const float* __restrict__ dsel,
                             const float* __restrict__ damping,
                             const float* __restrict__ noise,
                             float2* __restrict__ A) {
    const int b = blockIdx.x >> 4, f = blockIdx.x & 15;
    const int tid = threadIdx.x;                 // 256 threads
    __shared__ float Wrow[NDEL];
    __shared__ float dl[2048];
    __shared__ float red[256];

    // --- softmax over 512 delay logits for this (b,f), damping folded in ---
    float v0 = dsel[(b*NDEL + tid)*NFR + f];
    float v1 = dsel[(b*NDEL + tid + 256)*NFR + f];
    red[tid] = fmaxf(v0, v1);
    __syncthreads();
    for (int off = 128; off > 0; off >>= 1) {
        if (tid < off) red[tid] = fmaxf(red[tid], red[tid+off]);
        __syncthreads();
    }
    float M = red[0];
    __syncthreads();
    float e0 = expf(v0 - M), e1 = expf(v1 - M);
    Wrow[tid] = e0; Wrow[tid+256] = e1;
    red[tid] = e0 + e1;
    __syncthreads();
    for (int off = 128; off > 0; off >>= 1) {
        if (tid < off) red[tid] += red[tid+off];
        __syncthreads();
    }
    float S = red[0];
    float damp = 1.0f/(1.0f + expf(-damping[b])) * 0.9999f;
    float scale = damp / S;
    Wrow[tid] *= scale; Wrow[tid+256] *= scale;
    // zero the window accumulator
    for (int k = tid; k < 2048; k += 256) dl[k] = 0.0f;
    __syncthreads();

    const unsigned start = (unsigned)f << 11;
    const float fstart = (float)start;

    // --- Phase A: small t (1..63), block-uniform t, lanes over multiples ---
    for (unsigned t = 1; t < 64; ++t) {
        float wt = Wrow[t-1];
        unsigned q0 = (unsigned)(__fdividef(fstart, (float)t));
        unsigned n0 = q0 * t;
        while (n0 < start) n0 += t;
        while (n0 >= start + t) n0 -= t;
        for (unsigned i = (n0 - start) + (unsigned)tid * t; i < 2048u; i += 256u * t)
            atomicAdd(&dl[i], wt);
    }
    // --- Phase B: large t (64..512), lane-parallel over t ---
    for (unsigned t = 64u + (unsigned)tid; t <= 512u; t += 256u) {
        float wt = Wrow[t-1];
        unsigned q0 = (unsigned)(__fdividef(fstart, (float)t));
        unsigned n0 = q0 * t;
        while (n0 < start) n0 += t;
        while (n0 >= start + t) n0 -= t;
        for (unsigned i = n0 - start; i < 2048u; i += t)
            atomicAdd(&dl[i], wt);
    }
    __syncthreads();

    // --- epilogue: impulse^2 linear interp * noise, pack z = d + i*imp ---
    for (int k = tid; k < 2048; k += 256) {
        int n = (int)start + k;
        float pos = (n + 0.5f) * (1.0f/256.0f) - 0.5f;
        pos = fminf(fmaxf(pos, 0.0f), 127.0f);
        int i0 = (int)pos;
        float w = pos - (float)i0;
        int i1 = (i0 + 1 > 127) ? 127 : i0 + 1;
        float x0 = impulse[b*128 + i0]; x0 *= x0;
        float x1 = impulse[b*128 + i1]; x1 *= x1;
        float iv = (x0*(1.0f - w) + x1*w) * noise[b*NSAMP + n];
        A[b*NSAMP + n] = make_float2(dl[k], iv);
    }
}

// ---------------------------------------------------------------------------
// Four-step FFT, N = 32768 = 512*64, n = n1*64 + n2, k = k1 + 512*k2.
// Kernel 1: per-wave 512-pt FFT over n1 for each (s, n2); three radix-8
// Stockham stages through LDS; apply twiddle w_N^{n2*k1}; store [n2*512 + k1].
// If filt != nullptr (first inverse kernel): the load phase performs the
// Hermitian unpack of Z = FFT(d + i*imp), the filter-envelope multiply and
// the ortho scale (pointwise kernel fused in).
__global__ void fft512_kernel(const float2* __restrict__ src,
                              float2* __restrict__ dst,
                              const float* __restrict__ filt,
                              float sign) {
    const int wave = threadIdx.x >> 6, j = threadIdx.x & 63;
    const int s = blockIdx.x >> 4;
    const int n2 = ((blockIdx.x & 15) << 2) | wave;
    __shared__ float2 buf[4][2][576];
    __shared__ float fs[NFR];
    if (filt && threadIdx.x < NFR)
        fs[threadIdx.x] = 1.0f/(1.0f + expf(-filt[s*NFR + threadIdx.x]));
    __syncthreads();

    const float2* sp = src + s * NSAMP;
    float2 v[8], X[8];
    if (!filt) {
#pragma unroll
        for (int q = 0; q < 8; ++q) v[q] = sp[64*j + 4096*q + n2];
    } else {
        const float SCALE = 1.0f / (32768.0f * 181.01933598375618f); // N^{-3/2}
#pragma unroll
        for (int q = 0; q < 8; ++q) {
            int m = 64*j + 4096*q + n2;
            float2 Zk = sp[m];
            float2 Zr = sp[(NSAMP - m) & (NSAMP - 1)];
            float2 Zrc = make_float2(Zr.x, -Zr.y);
            float2 D = make_float2(0.5f*(Zk.x + Zrc.x), 0.5f*(Zk.y + Zrc.y));
            float2 df = make_float2(Zk.x - Zrc.x, Zk.y - Zrc.y);
            float2 I = make_float2(0.5f*df.y, -0.5f*df.x);
            int jjb = (m <= NSAMP - m) ? m : NSAMP - m;
            float fv = 0.0f;
            if (jjb < NSAMP/2) {
                float pos = (jjb + 0.5f) * (1.0f/1024.0f) - 0.5f;
                pos = fminf(fmaxf(pos, 0.0f), 15.0f);
                int i0 = (int)pos;
                float w = pos - (float)i0;
                int i1 = (i0 + 1 > 15) ? 15 : i0 + 1;
                fv = fs[i0]*(1.0f - w) + fs[i1]*w;
            }
            float2 spc = cmul(D, I);
            float g = fv * SCALE;
            v[q] = make_float2(spc.x * g, spc.y * g);
        }
    }

    // stage 1 (lNs=0)
    bfly8(v, sign, X);
#pragma unroll
    for (int r = 0; r < 8; ++r) buf[wave][0][phi(8*j + r)] = X[r];
    __syncthreads();
    // stage 2 (lNs=3)
#pragma unroll
    for (int q = 0; q < 8; ++q) v[q] = buf[wave][0][phi(j + 64*q)];
    int jm = j & 7;
    twiddle_q(v, sign * TWO_PI * (float)jm * (1.0f/64.0f));
    bfly8(v, sign, X);
#pragma unroll
    for (int r = 0; r < 8; ++r) buf[wave][1][phi(((j>>3)<<6) + jm + (r<<3))] = X[r];
    __syncthreads();
    // stage 3 (lNs=6) -> natural order k1 = j + 64r
#pragma unroll
    for (int q = 0; q < 8; ++q) v[q] = buf[wave][1][phi(j + 64*q)];
    twiddle_q(v, sign * TWO_PI * (float)j * (1.0f/512.0f));
    bfly8(v, sign, X);

    // four-step twiddle w_N^{n2*k1}, store G[n2*512 + k1] (coalesced)
    float2* dp = dst + s * NSAMP + n2 * 512;
#pragma unroll
    for (int r = 0; r < 8; ++r) {
        int k1 = j + 64*r;
        int pr = (n2 * k1) & (NSAMP - 1);
        float sa, ca; __sincosf(sign * TWO_PI * (float)pr * (1.0f/32768.0f), &sa, &ca);
        dp[k1] = cmul(X[r], make_float2(ca, sa));
    }
}

// ---------------------------------------------------------------------------
// Kernel 2: 64-pt FFT over n2 for each k1 (two radix-8 stages).
// Each wave handles 8 sub-FFTs: lane = c + 8*jj (c = which FFT, jj = position).
// Output X[k1 + 512*k2] in natural order; if out_real, store Re() only.
__global__ void fft64_kernel(const float2* __restrict__ src,
                             float2* __restrict__ dst,
                             float* __restrict__ out_real,
                             float sign) {
    const int wave = threadIdx.x >> 6, l = threadIdx.x & 63;
    const int c = l & 7, jj = l >> 3;
    const int s = blockIdx.x >> 4;
    const int k1base = (((blockIdx.x & 15) << 2) | wave) << 3;
    __shared__ float2 buf[4][576];

    const float2* sp = src + s * NSAMP;
    float2 v[8], X[8];
#pragma unroll
    for (int q = 0; q < 8; ++q) v[q] = sp[(jj + 8*q)*512 + k1base + c];

    // stage 1 (lNs=0)
    bfly8(v, sign, X);
#pragma unroll
    for (int r = 0; r < 8; ++r) buf[wave][phi(c*64 + jj*8 + r)] = X[r];
    __syncthreads();
    // stage 2 (lNs=3) -> k2 = jj + 8r
#pragma unroll
    for (int q = 0; q < 8; ++q) v[q] = buf[wave][phi(c*64 + jj + 8*q)];
    twiddle_q(v, sign * TWO_PI * (float)jj * (1.0f/64.0f));
    bfly8(v, sign, X);

    int base = s * NSAMP + k1base + c;
    if (out_real) {
#pragma unroll
        for (int r = 0; r < 8; ++r) out_real[base + 512*(jj + 8*r)] = X[r].x;
    } else {
#pragma unroll
        for (int r = 0; r < 8; ++r) dst[base + 512*(jj + 8*r)] = X[r];
    }
}

// ---------------------------------------------------------------------------
extern "C" void kernel_launch(void* const* d_in, const int* in_sizes, int n_in,
                              void* d_out, int out_size, void* d_ws, size_t ws_size,
                              hipStream_t stream) {
    const float* impulse = (const float*)d_in[0];   // [8,128]
    const float* dsel    = (const float*)d_in[1];   // [8,512,16]
    const float* damping = (const float*)d_in[2];   // [8,1]
    const float* filt    = (const float*)d_in[3];   // [8,16]
    const float* noise   = (const float*)d_in[4];   // [8,1,32768]
    // d_in[5] (delays, 64 MB): pure structure delays[i,n] = ((i+1) | n) — never read.
    float* out = (float*)d_out;                     // [8,32768]

    float2* A = (float2*)d_ws;                      // 2 MB
    float2* B = A + BATCH * NSAMP;                  // 2 MB

    // z = d + i*imp (softmax+sieve+interp fused)
    build_kernel<<<dim3(BATCH*NFR), dim3(256), 0, stream>>>(impulse, dsel, damping, noise, A);
    // forward FFT: Z in A
    fft512_kernel<<<dim3(128), dim3(256), 0, stream>>>(A, B, nullptr, -1.0f);
    fft64_kernel <<<dim3(128), dim3(256), 0, stream>>>(B, A, nullptr, -1.0f);
    // inverse FFT with pointwise (Hermitian unpack * filt * scale) fused in
    fft512_kernel<<<dim3(128), dim3(256), 0, stream>>>(A, B, filt, 1.0f);
    fft64_kernel <<<dim3(128), dim3(256), 0, stream>>>(B, nullptr, out, 1.0f);
}

// Round 3
// 143.199 us; speedup vs baseline: 1.2342x; 1.0356x over previous
//
#include <hip/hip_runtime.h>
#include <math.h>

#define NSAMP 32768   // 2^15 = 512 * 64
#define NDEL  512
#define NFR   16
#define BATCH 8
#define TWO_PI 6.283185307179586f

__device__ __forceinline__ float2 cmul(float2 a, float2 b) {
    return make_float2(a.x*b.x - a.y*b.y, a.x*b.y + a.y*b.x);
}
__device__ __forceinline__ float2 cadd(float2 a, float2 b){ return make_float2(a.x+b.x, a.y+b.y); }
__device__ __forceinline__ float2 csub(float2 a, float2 b){ return make_float2(a.x-b.x, a.y-b.y); }
// multiply by sign*i : fwd(sign=-1) -> -i*z = (y,-x) ; inv(+1) -> +i*z = (-y,x)
__device__ __forceinline__ float2 crot(float2 z, float sign){ return make_float2(-sign*z.y, sign*z.x); }

// LDS index swizzle to break power-of-2 strides (i -> i + i/8)
__device__ __forceinline__ int phi(int i){ return i + (i >> 3); }

__device__ __forceinline__ void bfly8(const float2 v[8], float sign, float2 X[8]) {
    const float S2 = 0.70710678118654752f;
    float2 t0 = cadd(v[0], v[4]), t1 = csub(v[0], v[4]);
    float2 t2 = cadd(v[2], v[6]), t3 = crot(csub(v[2], v[6]), sign);
    float2 E0 = cadd(t0, t2), E1 = cadd(t1, t3), E2 = csub(t0, t2), E3 = csub(t1, t3);
    float2 u0 = cadd(v[1], v[5]), u1 = csub(v[1], v[5]);
    float2 u2 = cadd(v[3], v[7]), u3 = crot(csub(v[3], v[7]), sign);
    float2 O0 = cadd(u0, u2), O1 = cadd(u1, u3), O2 = csub(u0, u2), O3 = csub(u1, u3);
    float2 c1 = make_float2( S2, sign*S2);
    float2 c3 = make_float2(-S2, sign*S2);
    float2 w1o = cmul(c1, O1);
    float2 w2o = crot(O2, sign);
    float2 w3o = cmul(c3, O3);
    X[0]=cadd(E0,O0);  X[4]=csub(E0,O0);
    X[1]=cadd(E1,w1o); X[5]=csub(E1,w1o);
    X[2]=cadd(E2,w2o); X[6]=csub(E2,w2o);
    X[3]=cadd(E3,w3o); X[7]=csub(E3,w3o);
}

__device__ __forceinline__ void twiddle_q(float2 v[8], float ang1) {
    float sa, ca; __sincosf(ang1, &sa, &ca);
    float2 w1 = make_float2(ca, sa), wq = w1;
#pragma unroll
    for (int q = 1; q < 8; ++q) { v[q] = cmul(v[q], wq); wq = cmul(wq, w1); }
}

// ---------------------------------------------------------------------------
// Fused softmax + damping + divisor-sieve + impulse/noise build.
// One wave-block per (b, f, quarter): 512-sample window. Softmax over the 512
// delay logits recomputed per block (cheap); d[n] = sum_{t|n, t<=512} W[t-1]
// sieved into LDS.  Grid: 8*16*4 = 512 blocks x 64 threads.
__global__ void build_kernel(const float* __restrict__ impulse,
                             const float* __restrict__ dsel,
                             const float* __restrict__ damping,
                             const float* __restrict__ noise,
                             float2* __restrict__ A) {
    const int b   = blockIdx.x >> 6;
    const int f   = (blockIdx.x >> 2) & 15;
    const int sub = blockIdx.x & 3;
    const int tid = threadIdx.x;                 // 64 threads
    __shared__ float Wrow[NDEL];
    __shared__ float dl[512];
    __shared__ float red[64];

    // --- softmax over 512 delay logits for this (b,f), damping folded in ---
    float v[8], m = -1e30f;
#pragma unroll
    for (int k = 0; k < 8; ++k) {
        v[k] = dsel[(b*NDEL + tid + 64*k)*NFR + f];
        m = fmaxf(m, v[k]);
    }
    red[tid] = m;
    __syncthreads();
    for (int off = 32; off > 0; off >>= 1) {
        if (tid < off) red[tid] = fmaxf(red[tid], red[tid+off]);
        __syncthreads();
    }
    float M = red[0];
    __syncthreads();
    float e[8], s = 0.0f;
#pragma unroll
    for (int k = 0; k < 8; ++k) { e[k] = expf(v[k] - M); s += e[k]; }
    red[tid] = s;
    __syncthreads();
    for (int off = 32; off > 0; off >>= 1) {
        if (tid < off) red[tid] += red[tid+off];
        __syncthreads();
    }
    float S = red[0];
    float damp = 1.0f/(1.0f + expf(-damping[b])) * 0.9999f;
    float scale = damp / S;
#pragma unroll
    for (int k = 0; k < 8; ++k) Wrow[tid + 64*k] = e[k] * scale;
    for (int k = tid; k < 512; k += 64) dl[k] = 0.0f;
    __syncthreads();

    const unsigned start = ((unsigned)f << 11) + ((unsigned)sub << 9);
    const float fstart = (float)start;

    // --- Phase A: small t (1..63), block-uniform t, lanes over multiples ---
    for (unsigned t = 1; t < 64; ++t) {
        float wt = Wrow[t-1];
        unsigned q0 = (unsigned)(__fdividef(fstart, (float)t));
        unsigned n0 = q0 * t;
        while (n0 < start) n0 += t;
        while (n0 >= start + t) n0 -= t;
        for (unsigned i = (n0 - start) + (unsigned)tid * t; i < 512u; i += 64u * t)
            atomicAdd(&dl[i], wt);
    }
    // --- Phase B: large t (64..512), lane-parallel over t ---
    for (unsigned t = 64u + (unsigned)tid; t <= 512u; t += 64u) {
        float wt = Wrow[t-1];
        unsigned q0 = (unsigned)(__fdividef(fstart, (float)t));
        unsigned n0 = q0 * t;
        while (n0 < start) n0 += t;
        while (n0 >= start + t) n0 -= t;
        for (unsigned i = n0 - start; i < 512u; i += t)
            atomicAdd(&dl[i], wt);
    }
    __syncthreads();

    // --- epilogue: impulse^2 linear interp * noise, pack z = d + i*imp ---
    for (int k = tid; k < 512; k += 64) {
        int n = (int)start + k;
        float pos = (n + 0.5f) * (1.0f/256.0f) - 0.5f;
        pos = fminf(fmaxf(pos, 0.0f), 127.0f);
        int i0 = (int)pos;
        float w = pos - (float)i0;
        int i1 = (i0 + 1 > 127) ? 127 : i0 + 1;
        float x0 = impulse[b*128 + i0]; x0 *= x0;
        float x1 = impulse[b*128 + i1]; x1 *= x1;
        float iv = (x0*(1.0f - w) + x1*w) * noise[b*NSAMP + n];
        A[b*NSAMP + n] = make_float2(dl[k], iv);
    }
}

// ---------------------------------------------------------------------------
// Four-step FFT, N = 32768 = 512*64, n = n1*64 + n2, k = k1 + 512*k2.
// Kernel 1: one wave-block per (s, n2) -> 512 blocks x 64 threads. Three
// radix-8 Stockham stages through per-wave LDS; apply twiddle w_N^{n2*k1};
// store [n2*512 + k1]. If filt != nullptr (first inverse kernel): load phase
// does the Hermitian unpack of Z = FFT(d + i*imp), filter multiply, and the
// combined ortho scale (pointwise fused in).
__global__ void fft512_kernel(const float2* __restrict__ src,
                              float2* __restrict__ dst,
                              const float* __restrict__ filt,
                              float sign) {
    const int j  = threadIdx.x;          // 64
    const int s  = blockIdx.x >> 6;
    const int n2 = blockIdx.x & 63;
    __shared__ float2 buf[2][576];
    __shared__ float fs[NFR];
    if (filt && j < NFR)
        fs[j] = 1.0f/(1.0f + expf(-filt[s*NFR + j]));
    __syncthreads();

    const float2* sp = src + s * NSAMP;
    float2 v[8], X[8];
    if (!filt) {
#pragma unroll
        for (int q = 0; q < 8; ++q) v[q] = sp[64*j + 4096*q + n2];
    } else {
        const float SCALE = 1.0f / (32768.0f * 181.01933598375618f); // N^{-3/2}
#pragma unroll
        for (int q = 0; q < 8; ++q) {
            int m = 64*j + 4096*q + n2;
            float2 Zk = sp[m];
            float2 Zr = sp[(NSAMP - m) & (NSAMP - 1)];
            float2 Zrc = make_float2(Zr.x, -Zr.y);
            float2 D = make_float2(0.5f*(Zk.x + Zrc.x), 0.5f*(Zk.y + Zrc.y));
            float2 df = make_float2(Zk.x - Zrc.x, Zk.y - Zrc.y);
            float2 I = make_float2(0.5f*df.y, -0.5f*df.x);
            int jjb = (m <= NSAMP - m) ? m : NSAMP - m;
            float fv = 0.0f;
            if (jjb < NSAMP/2) {
                float pos = (jjb + 0.5f) * (1.0f/1024.0f) - 0.5f;
                pos = fminf(fmaxf(pos, 0.0f), 15.0f);
                int i0 = (int)pos;
                float w = pos - (float)i0;
                int i1 = (i0 + 1 > 15) ? 15 : i0 + 1;
                fv = fs[i0]*(1.0f - w) + fs[i1]*w;
            }
            float2 spc = cmul(D, I);
            float g = fv * SCALE;
            v[q] = make_float2(spc.x * g, spc.y * g);
        }
    }

    // stage 1 (lNs=0)
    bfly8(v, sign, X);
#pragma unroll
    for (int r = 0; r < 8; ++r) buf[0][phi(8*j + r)] = X[r];
    __syncthreads();
    // stage 2 (lNs=3)
#pragma unroll
    for (int q = 0; q < 8; ++q) v[q] = buf[0][phi(j + 64*q)];
    int jm = j & 7;
    twiddle_q(v, sign * TWO_PI * (float)jm * (1.0f/64.0f));
    bfly8(v, sign, X);
#pragma unroll
    for (int r = 0; r < 8; ++r) buf[1][phi(((j>>3)<<6) + jm + (r<<3))] = X[r];
    __syncthreads();
    // stage 3 (lNs=6) -> natural order k1 = j + 64r
#pragma unroll
    for (int q = 0; q < 8; ++q) v[q] = buf[1][phi(j + 64*q)];
    twiddle_q(v, sign * TWO_PI * (float)j * (1.0f/512.0f));
    bfly8(v, sign, X);

    // four-step twiddle w_N^{n2*k1}, store G[n2*512 + k1] (coalesced)
    float2* dp = dst + s * NSAMP + n2 * 512;
#pragma unroll
    for (int r = 0; r < 8; ++r) {
        int k1 = j + 64*r;
        int pr = (n2 * k1) & (NSAMP - 1);
        float sa, ca; __sincosf(sign * TWO_PI * (float)pr * (1.0f/32768.0f), &sa, &ca);
        dp[k1] = cmul(X[r], make_float2(ca, sa));
    }
}

// ---------------------------------------------------------------------------
// Kernel 2: 64-pt FFT over n2 for each k1 (two radix-8 stages). One wave-block
// handles 8 sub-FFTs: lane = c + 8*jj (c = which FFT, jj = position).
// Grid: 512 blocks x 64 threads. Output X[k1 + 512*k2] natural order; if
// out_real, store Re() only.
__global__ void fft64_kernel(const float2* __restrict__ src,
                             float2* __restrict__ dst,
                             float* __restrict__ out_real,
                             float sign) {
    const int l = threadIdx.x;           // 64
    const int c = l & 7, jj = l >> 3;
    const int s = blockIdx.x >> 6;
    const int k1base = (blockIdx.x & 63) << 3;
    __shared__ float2 buf[576];

    const float2* sp = src + s * NSAMP;
    float2 v[8], X[8];
#pragma unroll
    for (int q = 0; q < 8; ++q) v[q] = sp[(jj + 8*q)*512 + k1base + c];

    // stage 1 (lNs=0)
    bfly8(v, sign, X);
#pragma unroll
    for (int r = 0; r < 8; ++r) buf[phi(c*64 + jj*8 + r)] = X[r];
    __syncthreads();
    // stage 2 (lNs=3) -> k2 = jj + 8r
#pragma unroll
    for (int q = 0; q < 8; ++q) v[q] = buf[phi(c*64 + jj + 8*q)];
    twiddle_q(v, sign * TWO_PI * (float)jj * (1.0f/64.0f));
    bfly8(v, sign, X);

    int base = s * NSAMP + k1base + c;
    if (out_real) {
#pragma unroll
        for (int r = 0; r < 8; ++r) out_real[base + 512*(jj + 8*r)] = X[r].x;
    } else {
#pragma unroll
        for (int r = 0; r < 8; ++r) dst[base + 512*(jj + 8*r)] = X[r];
    }
}

// ---------------------------------------------------------------------------
extern "C" void kernel_launch(void* const* d_in, const int* in_sizes, int n_in,
                              void* d_out, int out_size, void* d_ws, size_t ws_size,
                              hipStream_t stream) {
    const float* impulse = (const float*)d_in[0];   // [8,128]
    const float* dsel    = (const float*)d_in[1];   // [8,512,16]
    const float* damping = (const float*)d_in[2];   // [8,1]
    const float* filt    = (const float*)d_in[3];   // [8,16]
    const float* noise   = (const float*)d_in[4];   // [8,1,32768]
    // d_in[5] (delays, 64 MB): pure structure delays[i,n] = ((i+1) | n) — never read.
    float* out = (float*)d_out;                     // [8,32768]

    float2* A = (float2*)d_ws;                      // 2 MB
    float2* B = A + BATCH * NSAMP;                  // 2 MB

    // z = d + i*imp (softmax+sieve+interp fused); 512 wave-blocks
    build_kernel<<<dim3(512), dim3(64), 0, stream>>>(impulse, dsel, damping, noise, A);
    // forward FFT: Z in A
    fft512_kernel<<<dim3(512), dim3(64), 0, stream>>>(A, B, nullptr, -1.0f);
    fft64_kernel <<<dim3(512), dim3(64), 0, stream>>>(B, A, nullptr, -1.0f);
    // inverse FFT with pointwise (Hermitian unpack * filt * scale) fused in
    fft512_kernel<<<dim3(512), dim3(64), 0, stream>>>(A, B, filt, 1.0f);
    fft64_kernel <<<dim3(512), dim3(64), 0, stream>>>(B, nullptr, out, 1.0f);
}

// Round 4
// 136.992 us; speedup vs baseline: 1.2901x; 1.0453x over previous
//
#include <hip/hip_runtime.h>
#include <math.h>

#define NSAMP 32768   // 2^15 = 512 * 64
#define NDEL  512
#define NFR   16
#define BATCH 8
#define TWO_PI 6.283185307179586f

__device__ __forceinline__ float2 cmul(float2 a, float2 b) {
    return make_float2(a.x*b.x - a.y*b.y, a.x*b.y + a.y*b.x);
}
__device__ __forceinline__ float2 cadd(float2 a, float2 b){ return make_float2(a.x+b.x, a.y+b.y); }
__device__ __forceinline__ float2 csub(float2 a, float2 b){ return make_float2(a.x-b.x, a.y-b.y); }
// multiply by sign*i : fwd(sign=-1) -> -i*z = (y,-x) ; inv(+1) -> +i*z = (-y,x)
__device__ __forceinline__ float2 crot(float2 z, float sign){ return make_float2(-sign*z.y, sign*z.x); }

// LDS index swizzle to break power-of-2 strides (i -> i + i/8)
__device__ __forceinline__ int phi(int i){ return i + (i >> 3); }

__device__ __forceinline__ void bfly8(const float2 v[8], float sign, float2 X[8]) {
    const float S2 = 0.70710678118654752f;
    float2 t0 = cadd(v[0], v[4]), t1 = csub(v[0], v[4]);
    float2 t2 = cadd(v[2], v[6]), t3 = crot(csub(v[2], v[6]), sign);
    float2 E0 = cadd(t0, t2), E1 = cadd(t1, t3), E2 = csub(t0, t2), E3 = csub(t1, t3);
    float2 u0 = cadd(v[1], v[5]), u1 = csub(v[1], v[5]);
    float2 u2 = cadd(v[3], v[7]), u3 = crot(csub(v[3], v[7]), sign);
    float2 O0 = cadd(u0, u2), O1 = cadd(u1, u3), O2 = csub(u0, u2), O3 = csub(u1, u3);
    float2 c1 = make_float2( S2, sign*S2);
    float2 c3 = make_float2(-S2, sign*S2);
    float2 w1o = cmul(c1, O1);
    float2 w2o = crot(O2, sign);
    float2 w3o = cmul(c3, O3);
    X[0]=cadd(E0,O0);  X[4]=csub(E0,O0);
    X[1]=cadd(E1,w1o); X[5]=csub(E1,w1o);
    X[2]=cadd(E2,w2o); X[6]=csub(E2,w2o);
    X[3]=cadd(E3,w3o); X[7]=csub(E3,w3o);
}

__device__ __forceinline__ void twiddle_q(float2 v[8], float ang1) {
    float sa, ca; __sincosf(ang1, &sa, &ca);
    float2 w1 = make_float2(ca, sa), wq = w1;
#pragma unroll
    for (int q = 1; q < 8; ++q) { v[q] = cmul(v[q], wq); wq = cmul(wq, w1); }
}

// ---------------------------------------------------------------------------
// Fused softmax + damping + divisor-sieve + impulse/noise build.
// One wave-block per (b, f, quarter): 512-sample window. d[n] = sum_{t|n,
// t<=512} W[t-1] sieved into LDS. Output written TRANSPOSED:
// A_T[b][n2][n1] with n = 64*n1 + n2 -> thread t (= n2) writes 8 consecutive
// complex (64 B contiguous), so the fft512 consumer loads coalesced.
__global__ void build_kernel(const float* __restrict__ impulse,
                             const float* __restrict__ dsel,
                             const float* __restrict__ damping,
                             const float* __restrict__ noise,
                             float2* __restrict__ At) {
    const int b   = blockIdx.x >> 6;
    const int f   = (blockIdx.x >> 2) & 15;
    const int sub = blockIdx.x & 3;
    const int tid = threadIdx.x;                 // 64 threads
    __shared__ float Wrow[NDEL];
    __shared__ float dl[512];
    __shared__ float red[64];

    // --- softmax over 512 delay logits for this (b,f), damping folded in ---
    float v[8], m = -1e30f;
#pragma unroll
    for (int k = 0; k < 8; ++k) {
        v[k] = dsel[(b*NDEL + tid + 64*k)*NFR + f];
        m = fmaxf(m, v[k]);
    }
    red[tid] = m;
    __syncthreads();
    for (int off = 32; off > 0; off >>= 1) {
        if (tid < off) red[tid] = fmaxf(red[tid], red[tid+off]);
        __syncthreads();
    }
    float M = red[0];
    __syncthreads();
    float e[8], s = 0.0f;
#pragma unroll
    for (int k = 0; k < 8; ++k) { e[k] = expf(v[k] - M); s += e[k]; }
    red[tid] = s;
    __syncthreads();
    for (int off = 32; off > 0; off >>= 1) {
        if (tid < off) red[tid] += red[tid+off];
        __syncthreads();
    }
    float S = red[0];
    float damp = 1.0f/(1.0f + expf(-damping[b])) * 0.9999f;
    float scale = damp / S;
#pragma unroll
    for (int k = 0; k < 8; ++k) Wrow[tid + 64*k] = e[k] * scale;
    for (int k = tid; k < 512; k += 64) dl[k] = 0.0f;
    __syncthreads();

    const unsigned start = ((unsigned)f << 11) + ((unsigned)sub << 9);
    const float fstart = (float)start;

    // --- Phase A: small t (1..63), block-uniform t, lanes over multiples ---
    for (unsigned t = 1; t < 64; ++t) {
        float wt = Wrow[t-1];
        unsigned q0 = (unsigned)(__fdividef(fstart, (float)t));
        unsigned n0 = q0 * t;
        while (n0 < start) n0 += t;
        while (n0 >= start + t) n0 -= t;
        for (unsigned i = (n0 - start) + (unsigned)tid * t; i < 512u; i += 64u * t)
            atomicAdd(&dl[i], wt);
    }
    // --- Phase B: large t (64..512), lane-parallel over t ---
    for (unsigned t = 64u + (unsigned)tid; t <= 512u; t += 64u) {
        float wt = Wrow[t-1];
        unsigned q0 = (unsigned)(__fdividef(fstart, (float)t));
        unsigned n0 = q0 * t;
        while (n0 < start) n0 += t;
        while (n0 >= start + t) n0 -= t;
        for (unsigned i = n0 - start; i < 512u; i += t)
            atomicAdd(&dl[i], wt);
    }
    __syncthreads();

    // --- epilogue: impulse^2 linear interp * noise; thread t = n2, writes
    //     8 consecutive n1 slots of the transposed layout ---
    const int n1base = (int)(start >> 6);        // f*32 + sub*8
    float2* op = At + b*NSAMP + tid*512 + n1base;
#pragma unroll
    for (int q = 0; q < 8; ++q) {
        int n = (int)start + tid + 64*q;
        float pos = (n + 0.5f) * (1.0f/256.0f) - 0.5f;
        pos = fminf(fmaxf(pos, 0.0f), 127.0f);
        int i0 = (int)pos;
        float w = pos - (float)i0;
        int i1 = (i0 + 1 > 127) ? 127 : i0 + 1;
        float x0 = impulse[b*128 + i0]; x0 *= x0;
        float x1 = impulse[b*128 + i1]; x1 *= x1;
        float iv = (x0*(1.0f - w) + x1*w) * noise[b*NSAMP + n];
        op[q] = make_float2(dl[tid + 64*q], iv);
    }
}

// ---------------------------------------------------------------------------
// Four-step FFT, N = 32768 = 512*64, n = n1*64 + n2, k = k1 + 512*k2.
// Kernel 1: one wave-block per (s, n2) -> 512 blocks x 64 threads. INPUT IS
// TRANSPOSED: src_T[n2*512 + n1] -> loads fully coalesced. Three radix-8
// Stockham stages through LDS; apply twiddle w_N^{n2*k1}; store [n2*512+k1].
// If filt != nullptr (first inverse kernel): load phase does the Hermitian
// unpack of Z = FFT(d + i*imp) (partner bin N-m lives at row (64-n2)&63,
// col 511-n1 — also coalesced), filter multiply, and the ortho scale.
__global__ void fft512_kernel(const float2* __restrict__ src,
                              float2* __restrict__ dst,
                              const float* __restrict__ filt,
                              float sign) {
    const int j  = threadIdx.x;          // 64
    const int s  = blockIdx.x >> 6;
    const int n2 = blockIdx.x & 63;
    __shared__ float2 buf[2][576];
    __shared__ float fs[NFR];
    if (filt && j < NFR)
        fs[j] = 1.0f/(1.0f + expf(-filt[s*NFR + j]));
    __syncthreads();

    const float2* sp = src + s * NSAMP;
    float2 v[8], X[8];
    if (!filt) {
#pragma unroll
        for (int q = 0; q < 8; ++q) v[q] = sp[n2*512 + j + 64*q];
    } else {
        const float SCALE = 1.0f / (32768.0f * 181.01933598375618f); // N^{-3/2}
        const int prow = (64 - n2) & 63;
#pragma unroll
        for (int q = 0; q < 8; ++q) {
            int n1 = j + 64*q;
            int m  = 64*n1 + n2;                     // natural bin index
            float2 Zk = sp[n2*512 + n1];
            int pcol = n2 ? (511 - n1) : ((512 - n1) & 511);
            float2 Zr = sp[prow*512 + pcol];         // Z[N-m]
            float2 Zrc = make_float2(Zr.x, -Zr.y);
            float2 D = make_float2(0.5f*(Zk.x + Zrc.x), 0.5f*(Zk.y + Zrc.y));
            float2 df = make_float2(Zk.x - Zrc.x, Zk.y - Zrc.y);
            float2 I = make_float2(0.5f*df.y, -0.5f*df.x);
            int jjb = (m <= NSAMP - m) ? m : NSAMP - m;
            float fv = 0.0f;
            if (jjb < NSAMP/2) {
                float pos = (jjb + 0.5f) * (1.0f/1024.0f) - 0.5f;
                pos = fminf(fmaxf(pos, 0.0f), 15.0f);
                int i0 = (int)pos;
                float w = pos - (float)i0;
                int i1 = (i0 + 1 > 15) ? 15 : i0 + 1;
                fv = fs[i0]*(1.0f - w) + fs[i1]*w;
            }
            float2 spc = cmul(D, I);
            float g = fv * SCALE;
            v[q] = make_float2(spc.x * g, spc.y * g);
        }
    }

    // stage 1 (lNs=0)
    bfly8(v, sign, X);
#pragma unroll
    for (int r = 0; r < 8; ++r) buf[0][phi(8*j + r)] = X[r];
    __syncthreads();
    // stage 2 (lNs=3)
#pragma unroll
    for (int q = 0; q < 8; ++q) v[q] = buf[0][phi(j + 64*q)];
    int jm = j & 7;
    twiddle_q(v, sign * TWO_PI * (float)jm * (1.0f/64.0f));
    bfly8(v, sign, X);
#pragma unroll
    for (int r = 0; r < 8; ++r) buf[1][phi(((j>>3)<<6) + jm + (r<<3))] = X[r];
    __syncthreads();
    // stage 3 (lNs=6) -> natural order k1 = j + 64r
#pragma unroll
    for (int q = 0; q < 8; ++q) v[q] = buf[1][phi(j + 64*q)];
    twiddle_q(v, sign * TWO_PI * (float)j * (1.0f/512.0f));
    bfly8(v, sign, X);

    // four-step twiddle w_N^{n2*k1}, store G[n2*512 + k1] (coalesced)
    float2* dp = dst + s * NSAMP + n2 * 512;
#pragma unroll
    for (int r = 0; r < 8; ++r) {
        int k1 = j + 64*r;
        int pr = (n2 * k1) & (NSAMP - 1);
        float sa, ca; __sincosf(sign * TWO_PI * (float)pr * (1.0f/32768.0f), &sa, &ca);
        dp[k1] = cmul(X[r], make_float2(ca, sa));
    }
}

// ---------------------------------------------------------------------------
// Kernel 2: 64-pt FFT over n2 for each k1 (two radix-8 stages). One wave-block
// handles 8 sub-FFTs: lane = c + 8*jj. Grid: 512 blocks x 64 threads.
// If dstT != nullptr (forward): store Z TRANSPOSED for the inverse fft512:
//   Z_T[k&63][k>>6] with k = k1 + 512*k2 (scattered 8B stores, absorbed by L2).
// If out_real != nullptr (last inverse stage): store Re() in natural order.
__global__ void fft64_kernel(const float2* __restrict__ src,
                             float2* __restrict__ dstT,
                             float* __restrict__ out_real,
                             float sign) {
    const int l = threadIdx.x;           // 64
    const int c = l & 7, jj = l >> 3;
    const int s = blockIdx.x >> 6;
    const int k1base = (blockIdx.x & 63) << 3;
    __shared__ float2 buf[576];

    const float2* sp = src + s * NSAMP;
    float2 v[8], X[8];
#pragma unroll
    for (int q = 0; q < 8; ++q) v[q] = sp[(jj + 8*q)*512 + k1base + c];

    // stage 1 (lNs=0)
    bfly8(v, sign, X);
#pragma unroll
    for (int r = 0; r < 8; ++r) buf[phi(c*64 + jj*8 + r)] = X[r];
    __syncthreads();
    // stage 2 (lNs=3) -> k2 = jj + 8r
#pragma unroll
    for (int q = 0; q < 8; ++q) v[q] = buf[phi(c*64 + jj + 8*q)];
    twiddle_q(v, sign * TWO_PI * (float)jj * (1.0f/64.0f));
    bfly8(v, sign, X);

    const int k1 = k1base + c;
    if (out_real) {
        float* op = out_real + s * NSAMP + k1;
#pragma unroll
        for (int r = 0; r < 8; ++r) op[512*(jj + 8*r)] = X[r].x;
    } else {
        // transposed: row = k1&63, col = (k1>>6) + 8*k2, k2 = jj + 8r
        float2* dp = dstT + s * NSAMP + (k1 & 63)*512 + (k1 >> 6) + 8*jj;
#pragma unroll
        for (int r = 0; r < 8; ++r) dp[64*r] = X[r];
    }
}

// ---------------------------------------------------------------------------
extern "C" void kernel_launch(void* const* d_in, const int* in_sizes, int n_in,
                              void* d_out, int out_size, void* d_ws, size_t ws_size,
                              hipStream_t stream) {
    const float* impulse = (const float*)d_in[0];   // [8,128]
    const float* dsel    = (const float*)d_in[1];   // [8,512,16]
    const float* damping = (const float*)d_in[2];   // [8,1]
    const float* filt    = (const float*)d_in[3];   // [8,16]
    const float* noise   = (const float*)d_in[4];   // [8,1,32768]
    // d_in[5] (delays, 64 MB): pure structure delays[i,n] = ((i+1) | n) — never read.
    float* out = (float*)d_out;                     // [8,32768]

    float2* A = (float2*)d_ws;                      // 2 MB
    float2* B = A + BATCH * NSAMP;                  // 2 MB

    // z = d + i*imp, written transposed A_T[n2][n1]
    build_kernel<<<dim3(512), dim3(64), 0, stream>>>(impulse, dsel, damping, noise, A);
    // forward FFT: fft512 reads A_T coalesced; fft64 stores Z transposed into A
    fft512_kernel<<<dim3(512), dim3(64), 0, stream>>>(A, B, nullptr, -1.0f);
    fft64_kernel <<<dim3(512), dim3(64), 0, stream>>>(B, A, nullptr, -1.0f);
    // inverse FFT with pointwise fused; reads Z_T coalesced (both bins m, N-m)
    fft512_kernel<<<dim3(512), dim3(64), 0, stream>>>(A, B, filt, 1.0f);
    fft64_kernel <<<dim3(512), dim3(64), 0, stream>>>(B, nullptr, out, 1.0f);
}